// Round 5
// baseline (117.957 us; speedup 1.0000x reference)
//
#include <hip/hip_runtime.h>
#include <hip/hip_bf16.h>

#define B_  1024
#define LA  529   // token positions -> conv channels
#define EE  100   // embedding dim -> conv steps
#define NF  16    // conv filters
#define NT  50    // conv output steps
#define NS  25    // pooled steps
#define NU  100   // LSTM units
#define NJ  400   // 4*NU
#define PF  8     // e-prefetch depth
#define NBB 16    // batches per block in kernel B

typedef float  f32x4v __attribute__((ext_vector_type(4)));
typedef short  s16x8  __attribute__((ext_vector_type(8)));

__device__ __forceinline__ float leaky(float v) { return v >= 0.f ? v : 0.2f * v; }

union bfu { __hip_bfloat16 b; unsigned short u; };
__device__ __forceinline__ unsigned short f2bf(float x) { bfu t; t.b = __float2bfloat16(x); return t.u; }
__device__ __forceinline__ float bf2f(unsigned short u) { bfu t; t.u = u; return __bfloat162float(t.b); }

// ---------------- Kernel A: gather + conv + relu + maxpool ----------------
// 1024 blocks x 256 threads; block = one batch. Wave w owns CONTIGUOUS cols
// [133w, 133w+nc): token index and weight addresses are wave-uniform loop
// constants -> scalar (s_load) pipe; only the e-gather is a vector load with
// a loop-invariant voffset. Plain C++ FMA inner loop (compiler-scheduled).
__global__ __launch_bounds__(256) void conv_embed_kernel(
    const int*   __restrict__ tokens,
    const float* __restrict__ emb,
    const float* __restrict__ conv_w,   // [2][529][16]
    const float* __restrict__ conv_b,   // [16]
    float*       __restrict__ p_out)    // [B][25][16]
{
    __shared__ __align__(16) float part_lds[4][NT][NF];   // 12.8 KB
    __shared__ __align__(16) float y_lds[NT][NF];

    const int tid  = threadIdx.x;
    const int b    = blockIdx.x;
    const int lane = tid & 63;
    const int w    = __builtin_amdgcn_readfirstlane(tid >> 6);
    const int t    = lane < NT ? lane : (NT - 1);

    const int cbase = w * 133;
    const int NC    = (w < 3) ? 133 : 130;
    const int* __restrict__ tokb = tokens + (size_t)b * LA + cbase;

    float acc[NF];
#pragma unroll
    for (int f = 0; f < NF; ++f) acc[f] = 0.f;

#define LOAD_E(dst, i_) do { \
    const int i2 = (i_); \
    const int ic = (i2 < NC) ? i2 : 0; \
    float2 v = *(const float2*)(emb + (size_t)tokb[ic] * EE + 2 * t); \
    if (i2 >= NC) { v.x = 0.f; v.y = 0.f; } \
    (dst) = v; } while (0)

    float2 ebuf[PF];
#pragma unroll
    for (int j = 0; j < PF; ++j) LOAD_E(ebuf[j], j);

    for (int ig = 0; ig < 136; ig += PF) {   // 17 groups cover i = 0..135 >= NC
        float2 enxt[PF];
#pragma unroll
        for (int j = 0; j < PF; ++j) LOAD_E(enxt[j], ig + PF + j);
#pragma unroll
        for (int j = 0; j < PF; ++j) {
            const int i  = ig + j;
            const int cc = cbase + ((i < NC) ? i : 0);   // uniform; padded cols have e=0
            const float* __restrict__ wp0 = conv_w + (size_t)cc * NF;
            const float* __restrict__ wp1 = conv_w + (size_t)(LA + cc) * NF;
            const float e0 = ebuf[j].x, e1 = ebuf[j].y;
#pragma unroll
            for (int f = 0; f < NF; ++f)
                acc[f] += e0 * wp0[f] + e1 * wp1[f];
        }
#pragma unroll
        for (int j = 0; j < PF; ++j) ebuf[j] = enxt[j];
    }
#undef LOAD_E

    if (lane < NT) {
        float4* dst = (float4*)part_lds[w][lane];
#pragma unroll
        for (int q = 0; q < 4; ++q) dst[q] = ((float4*)acc)[q];
    }
    __syncthreads();

    // reduce 4 wave-partials + bias + relu -> y[50][16]
    if (tid < 200) {
        const int tr = tid >> 2, fq = tid & 3;
        float4 s0 = ((float4*)part_lds[0][tr])[fq];
        float4 s1 = ((float4*)part_lds[1][tr])[fq];
        float4 s2 = ((float4*)part_lds[2][tr])[fq];
        float4 s3 = ((float4*)part_lds[3][tr])[fq];
        float4 cb = ((const float4*)conv_b)[fq];
        float4 y;
        y.x = fmaxf(s0.x + s1.x + s2.x + s3.x + cb.x, 0.f);
        y.y = fmaxf(s0.y + s1.y + s2.y + s3.y + cb.y, 0.f);
        y.z = fmaxf(s0.z + s1.z + s2.z + s3.z + cb.z, 0.f);
        y.w = fmaxf(s0.w + s1.w + s2.w + s3.w + cb.w, 0.f);
        ((float4*)y_lds[tr])[fq] = y;
    }
    __syncthreads();

    // maxpool k=2 s=2 -> p[25][16]
    for (int idx = tid; idx < NS * NF; idx += 256) {
        const int s = idx >> 4, f = idx & 15;
        p_out[(size_t)b * (NS * NF) + idx] = fmaxf(y_lds[2 * s][f], y_lds[2 * s + 1][f]);
    }
}

// ---------------- Kernel B: MFMA LSTM + dense head + softmax ----------------
// 64 blocks x 512 threads (8 waves), 16 batches/block -> all 16 MFMA rows real.
// Z = H_aug @ RK_aug per step: A = [h(0..99); p_t(100..115); 1(116)] single
// bf16; B = RK_aug hi/lo split (2 terms), stationary in VGPRs (<=128).
__global__ __launch_bounds__(512, 2) void lstm_mfma_kernel(
    const float* __restrict__ p_in,    // [B][25][16]
    const float* __restrict__ k_lstm,  // [16][400]
    const float* __restrict__ rk,      // [100][400]
    const float* __restrict__ b_lstm,  // [400]
    const float* __restrict__ w1,      // [100][64]
    const float* __restrict__ b1,      // [64]
    const float* __restrict__ w2,      // [64][3]
    const float* __restrict__ b2,      // [3]
    float*       __restrict__ out)     // [B][3]
{
    __shared__ __align__(16) unsigned short a_lds[4][64][8]; // [chunk][slot][e], 4 KB
    __shared__ float z_lds[NJ][17];                          // pad 17: conflict-free, 27.2 KB
    __shared__ float h_f32[NBB][NU];                         // 6.4 KB
    __shared__ float d_lds[NBB * 64];                        // 4 KB

    const int tid  = threadIdx.x;
    const int lane = tid & 63;
    const int wid  = tid >> 6;
    const int b0   = blockIdx.x * NBB;

    // zero A-buffer (pad k=117..127 stays 0 forever)
    for (int i = tid; i < 4 * 64 * 8; i += 512) ((unsigned short*)a_lds)[i] = 0;

    // ---- stationary B-frags: augmented RK, hi/lo split. Wave owns tiles [ts,te). ----
    const int ts = (wid * 25) >> 3;
    const int te = ((wid + 1) * 25) >> 3;
    s16x8 bhi[4][4], blo[4][4];   // [tile][chunk], up to 4 tiles -> 128 VGPR
#pragma unroll
    for (int i = 0; i < 4; ++i) {
        if (ts + i < te) {
            const int jg = (ts + i) * 16 + (lane & 15);
#pragma unroll
            for (int c = 0; c < 4; ++c) {
                s16x8 h8, l8;
#pragma unroll
                for (int e = 0; e < 8; ++e) {
                    const int k = c * 32 + (lane >> 4) * 8 + e;
                    float x = 0.f;
                    if (k < NU)        x = rk[k * NJ + jg];
                    else if (k < 116)  x = k_lstm[(k - NU) * NJ + jg];
                    else if (k == 116) x = b_lstm[jg];
                    const unsigned short hb = f2bf(x);
                    h8[e] = (short)hb;
                    l8[e] = (short)f2bf(x - bf2f(hb));
                }
                bhi[i][c] = h8; blo[i][c] = l8;
            }
        }
    }
    __syncthreads();   // a_lds zeroing complete

    // initial p (t=0) slots + bias slot
    if (tid < 256) {
        const int pb = tid >> 4, pf = tid & 15;
        const float pv = p_in[(size_t)(b0 + pb) * (NS * NF) + pf];
        const int k = 100 + pf, c = k >> 5, ls = ((k >> 3) & 3) * 16 + pb, e = k & 7;
        a_lds[c][ls][e] = f2bf(pv);
    }
    if (tid < NBB) a_lds[3][32 + tid][4] = 0x3F80;   // k=116: bf16 1.0
    float cst[4] = {0.f, 0.f, 0.f, 0.f};
    __syncthreads();

#pragma unroll 1
    for (int t = 0; t < NS; ++t) {
        // prefetch p for t+1 (stalls only at the ds_write after gates)
        float pv = 0.f;
        int pb = 0, pf = 0;
        if (tid < 256) {
            pb = tid >> 4; pf = tid & 15;
            const int tn = (t + 1 < NS) ? t + 1 : NS - 1;
            pv = p_in[(size_t)(b0 + pb) * (NS * NF) + tn * NF + pf];
        }
        // ---- Z = A @ B (2-term) ----
        s16x8 ah[4];
#pragma unroll
        for (int c = 0; c < 4; ++c) ah[c] = ((const s16x8*)a_lds[c])[lane];
#pragma unroll
        for (int i = 0; i < 4; ++i) {
            if (ts + i < te) {
                f32x4v acc = {0.f, 0.f, 0.f, 0.f};
#pragma unroll
                for (int c = 0; c < 4; ++c) {
                    acc = __builtin_amdgcn_mfma_f32_16x16x32_bf16(ah[c], bhi[i][c], acc, 0, 0, 0);
                    acc = __builtin_amdgcn_mfma_f32_16x16x32_bf16(ah[c], blo[i][c], acc, 0, 0, 0);
                }
                const int jt = (ts + i) * 16 + (lane & 15);
                const int bq = (lane >> 4) * 4;
#pragma unroll
                for (int q = 0; q < 4; ++q) z_lds[jt][bq + q] = acc[q];
            }
        }
        __syncthreads();
        // ---- gates: 1600 (b,u) pairs over 512 threads (3 each + 64 tail) ----
#pragma unroll
        for (int kk = 0; kk < 3; ++kk) {
            const int p = tid + 512 * kk;
            const int gb = p & 15, gu = p >> 4;
            const float zi = z_lds[gu][gb];
            const float zf = z_lds[gu + 100][gb];
            const float zg = z_lds[gu + 200][gb];
            const float zo = z_lds[gu + 300][gb];
            const float ig  = 1.f / (1.f + __expf(-zi));
            const float fg_ = 1.f / (1.f + __expf(-zf));
            const float og  = 1.f / (1.f + __expf(-zo));
            cst[kk] = fg_ * cst[kk] + ig * leaky(zg);
            const float h = og * leaky(cst[kk]);
            h_f32[gb][gu] = h;
            const int c = gu >> 5, ls = ((gu >> 3) & 3) * 16 + gb, e = gu & 7;
            a_lds[c][ls][e] = f2bf(h);
        }
        if (tid < 64) {
            const int p = 1536 + tid;
            const int gb = p & 15, gu = p >> 4;
            const float zi = z_lds[gu][gb];
            const float zf = z_lds[gu + 100][gb];
            const float zg = z_lds[gu + 200][gb];
            const float zo = z_lds[gu + 300][gb];
            const float ig  = 1.f / (1.f + __expf(-zi));
            const float fg_ = 1.f / (1.f + __expf(-zf));
            const float og  = 1.f / (1.f + __expf(-zo));
            cst[3] = fg_ * cst[3] + ig * leaky(zg);
            const float h = og * leaky(cst[3]);
            h_f32[gb][gu] = h;
            const int c = gu >> 5, ls = ((gu >> 3) & 3) * 16 + gb, e = gu & 7;
            a_lds[c][ls][e] = f2bf(h);
        }
        // p slots for t+1
        if (tid < 256) {
            const int k = 100 + pf, c = k >> 5, ls = ((k >> 3) & 3) * 16 + pb, e = k & 7;
            a_lds[c][ls][e] = f2bf(pv);
        }
        __syncthreads();
    }

    // dense head: d = tanh(h @ w1 + b1), 1024 outputs / 512 threads
#pragma unroll
    for (int r = 0; r < 2; ++r) {
        const int o = tid + 512 * r;
        const int hb = o >> 6, m = o & 63;
        float a = b1[m];
#pragma unroll 4
        for (int u = 0; u < NU; ++u) a += h_f32[hb][u] * w1[u * 64 + m];
        d_lds[o] = tanhf(a);
    }
    __syncthreads();

    // logits + softmax (3 classes)
    if (tid < NBB) {
        float l0 = b2[0], l1 = b2[1], l2 = b2[2];
        for (int m = 0; m < 64; ++m) {
            const float d = d_lds[tid * 64 + m];
            l0 += d * w2[m * 3 + 0];
            l1 += d * w2[m * 3 + 1];
            l2 += d * w2[m * 3 + 2];
        }
        const float mx = fmaxf(l0, fmaxf(l1, l2));
        const float e0 = __expf(l0 - mx), e1 = __expf(l1 - mx), e2 = __expf(l2 - mx);
        const float inv = 1.f / (e0 + e1 + e2);
        out[(b0 + tid) * 3 + 0] = e0 * inv;
        out[(b0 + tid) * 3 + 1] = e1 * inv;
        out[(b0 + tid) * 3 + 2] = e2 * inv;
    }
}

extern "C" void kernel_launch(void* const* d_in, const int* in_sizes, int n_in,
                              void* d_out, int out_size, void* d_ws, size_t ws_size,
                              hipStream_t stream) {
    const int*   tokens = (const int*)  d_in[0];
    const float* emb    = (const float*)d_in[1];
    const float* conv_w = (const float*)d_in[2];
    const float* conv_b = (const float*)d_in[3];
    const float* k_lstm = (const float*)d_in[4];
    const float* rk     = (const float*)d_in[5];
    const float* b_lstm = (const float*)d_in[6];
    const float* w1     = (const float*)d_in[7];
    const float* b1     = (const float*)d_in[8];
    const float* w2     = (const float*)d_in[9];
    const float* b2     = (const float*)d_in[10];
    float* out  = (float*)d_out;
    float* p_ws = (float*)d_ws;   // [B][25][16] = 1.6 MB

    conv_embed_kernel<<<B_, 256, 0, stream>>>(tokens, emb, conv_w, conv_b, p_ws);
    lstm_mfma_kernel<<<B_ / NBB, 512, 0, stream>>>(p_ws, k_lstm, rk, b_lstm,
                                                   w1, b1, w2, b2, out);
}

// Round 7
// 96.552 us; speedup vs baseline: 1.2217x; 1.2217x over previous
//
#include <hip/hip_runtime.h>
#include <hip/hip_bf16.h>

#define B_  1024
#define LA  529   // token positions -> conv channels
#define EE  100   // embedding dim -> conv steps
#define NF  16    // conv filters
#define NT  50    // conv output steps
#define NS  25    // pooled steps
#define NU  100   // LSTM units
#define NJ  400   // 4*NU
#define PF  8     // e-prefetch depth
#define NBB 16    // batches per block in kernel B

typedef float    f32x4v __attribute__((ext_vector_type(4)));
typedef short    s16x8  __attribute__((ext_vector_type(8)));
typedef _Float16 h2v    __attribute__((ext_vector_type(2)));

__device__ __forceinline__ float leaky(float v) { return v >= 0.f ? v : 0.2f * v; }

union bfu { __hip_bfloat16 b; unsigned short u; };
__device__ __forceinline__ unsigned short f2bf(float x) { bfu t; t.b = __float2bfloat16(x); return t.u; }
__device__ __forceinline__ float bf2f(unsigned short u) { bfu t; t.u = u; return __bfloat162float(t.b); }

__device__ __forceinline__ unsigned int pkh2(float x, float y) {
    auto p = __builtin_amdgcn_cvt_pkrtz(x, y);   // __fp16 ext_vector(2)
    return __builtin_bit_cast(unsigned int, p);
}

__device__ __forceinline__ float fdot2h(unsigned int e, unsigned int w, float acc) {
#if __has_builtin(__builtin_amdgcn_fdot2)
    return __builtin_amdgcn_fdot2(__builtin_bit_cast(h2v, e),
                                  __builtin_bit_cast(h2v, w), acc, false);
#else
    h2v ev = __builtin_bit_cast(h2v, e), wv = __builtin_bit_cast(h2v, w);
    return acc + (float)ev.x * (float)wv.x + (float)ev.y * (float)wv.y;
#endif
}

// ---------------- Kernel P: fp32 -> fp16 conversion ----------------
// emb_h[i] = pack2(emb[2i],emb[2i+1]); convw_h[c*16+f] = (w0[c][f], w1[c][f])
__global__ __launch_bounds__(256) void prep_kernel(
    const float* __restrict__ emb,      // [V*E]
    const float* __restrict__ conv_w,   // [2][529][16]
    unsigned int* __restrict__ emb_h,   // [V*E/2] packed half2
    unsigned int* __restrict__ convw_h) // [529*16] packed (w0,w1)
{
    const int gid = blockIdx.x * 256 + threadIdx.x;
    const int stride = gridDim.x * 256;
    for (int i = gid; i < (15245 * 100) / 2; i += stride) {
        const float2 v = ((const float2*)emb)[i];
        emb_h[i] = pkh2(v.x, v.y);
    }
    for (int i = gid; i < LA * NF; i += stride)
        convw_h[i] = pkh2(conv_w[i], conv_w[LA * NF + i]);
}

// ---------------- Kernel A: gather + conv + relu + maxpool ----------------
// 1024 blocks x 256 threads; block = batch; wave w owns contiguous cols.
// fp16 table (L2-resident), weights in LDS, inner product via v_dot2_f32_f16.
__global__ __launch_bounds__(256) void conv_embed_kernel(
    const int*          __restrict__ tokens,
    const unsigned int* __restrict__ emb_h,   // [V][50] half2 rows
    const unsigned int* __restrict__ convw_h, // [529][16] (w0,w1) half2
    const float*        __restrict__ conv_b,
    float*              __restrict__ p_out)   // [B][25][16]
{
    __shared__ __align__(16) unsigned int smem[LA * NF];  // 33.9 KB (union)
    unsigned int* wlds = smem;
    float* part = (float*)smem;           // [4][50][16] after compute
    float* ylds = (float*)smem + 3200;    // [50][16]

    const int tid  = threadIdx.x;
    const int b    = blockIdx.x;
    const int lane = tid & 63;
    const int w    = __builtin_amdgcn_readfirstlane(tid >> 6);
    const int t    = lane < NT ? lane : (NT - 1);

    // stage interleaved weights
    for (int i = tid; i < (LA * NF) / 4; i += 256)
        ((uint4*)smem)[i] = ((const uint4*)convw_h)[i];
    __syncthreads();

    const int cbase = w * 133;
    const int NC    = (w < 3) ? 133 : 130;
    const int* __restrict__ tokb = tokens + (size_t)b * LA + cbase;

    float acc[NF];
#pragma unroll
    for (int f = 0; f < NF; ++f) acc[f] = 0.f;

#define LOAD_E(dst, i_) do { \
    const int i2 = (i_); \
    const int ic = (i2 < NC) ? i2 : 0; \
    unsigned int v = emb_h[(size_t)tokb[ic] * 50 + t]; \
    if (i2 >= NC) v = 0u; \
    (dst) = v; } while (0)

    unsigned int ebuf[PF];
#pragma unroll
    for (int j = 0; j < PF; ++j) LOAD_E(ebuf[j], j);

    for (int ig = 0; ig < 136; ig += PF) {   // 17 groups cover i = 0..135 >= NC
        unsigned int enxt[PF];
#pragma unroll
        for (int j = 0; j < PF; ++j) LOAD_E(enxt[j], ig + PF + j);
#pragma unroll
        for (int j = 0; j < PF; ++j) {
            const int i  = ig + j;
            const int cc = cbase + ((i < NC) ? i : 0);  // padded cols have e=0
            const unsigned int* wp = wlds + cc * NF;
            unsigned int wv[NF];
#pragma unroll
            for (int q = 0; q < 4; ++q) ((uint4*)wv)[q] = ((const uint4*)wp)[q];
#pragma unroll
            for (int f = 0; f < NF; ++f) acc[f] = fdot2h(ebuf[j], wv[f], acc[f]);
        }
#pragma unroll
        for (int j = 0; j < PF; ++j) ebuf[j] = enxt[j];
    }
#undef LOAD_E

    __syncthreads();   // all waves done reading wlds; reuse as part buffer
    if (lane < NT) {
        float4* dst = (float4*)(part + (size_t)(w * NT + lane) * NF);
#pragma unroll
        for (int q = 0; q < 4; ++q) dst[q] = ((float4*)acc)[q];
    }
    __syncthreads();

    // reduce 4 wave-partials + bias + relu -> y[50][16]
    if (tid < 200) {
        const int tr = tid >> 2, fq = tid & 3;
        float4 s0 = ((float4*)(part + (0 * NT + tr) * NF))[fq];
        float4 s1 = ((float4*)(part + (1 * NT + tr) * NF))[fq];
        float4 s2 = ((float4*)(part + (2 * NT + tr) * NF))[fq];
        float4 s3 = ((float4*)(part + (3 * NT + tr) * NF))[fq];
        float4 cb = ((const float4*)conv_b)[fq];
        float4 y;
        y.x = fmaxf(s0.x + s1.x + s2.x + s3.x + cb.x, 0.f);
        y.y = fmaxf(s0.y + s1.y + s2.y + s3.y + cb.y, 0.f);
        y.z = fmaxf(s0.z + s1.z + s2.z + s3.z + cb.z, 0.f);
        y.w = fmaxf(s0.w + s1.w + s2.w + s3.w + cb.w, 0.f);
        ((float4*)(ylds + tr * NF))[fq] = y;
    }
    __syncthreads();

    // maxpool k=2 s=2 -> p[25][16]
    for (int idx = tid; idx < NS * NF; idx += 256) {
        const int s = idx >> 4, f = idx & 15;
        p_out[(size_t)b * (NS * NF) + idx] =
            fmaxf(ylds[2 * s * NF + f], ylds[(2 * s + 1) * NF + f]);
    }
}

// ---------------- Kernel B: MFMA LSTM + dense head + softmax ----------------
// 64 blocks x 512 threads, 16 batches/block. Padded layout: 4 gates x 7
// u-tiles (NU padded to 112). Wave w (0..6) owns tiles (g=0..3, w) -> each
// lane holds zi,zf,zg,zo for its (u,b) pairs IN REGISTERS: no z_lds, gates
// in-register, ONE barrier/step. A double-buffered; wave 7 prefetches p(t+1).
__global__ __launch_bounds__(512, 2) void lstm_mfma_kernel(
    const float* __restrict__ p_in,    // [B][25][16]
    const float* __restrict__ k_lstm,  // [16][400]
    const float* __restrict__ rk,      // [100][400]
    const float* __restrict__ b_lstm,  // [400]
    const float* __restrict__ w1,      // [100][64]
    const float* __restrict__ b1,      // [64]
    const float* __restrict__ w2,      // [64][3]
    const float* __restrict__ b2,      // [3]
    float*       __restrict__ out)     // [B][3]
{
    __shared__ __align__(16) unsigned short a_lds[2][4][64][8]; // dbuf, 8 KB
    __shared__ float h_f32[NBB][NU];                            // 6.4 KB
    __shared__ float d_lds[NBB * 64];                           // 4 KB

    const int tid  = threadIdx.x;
    const int lane = tid & 63;
    const int wid  = tid >> 6;
    const int b0   = blockIdx.x * NBB;

    for (int i = tid; i < 2 * 4 * 64 * 8; i += 512) ((unsigned short*)a_lds)[i] = 0;

    // ---- stationary B-frags: wave w owns (gate g, u-tile w), hi/lo split ----
    s16x8 bhi[4][4], blo[4][4];   // [gate][chunk] = 128 VGPR
    const int col = lane & 15;
    const int jl  = wid * 16 + col;          // unit 0..111 (wid<7)
    const bool uvalid = (wid < 7) && (jl < NU);
    if (wid < 7) {
#pragma unroll
        for (int g = 0; g < 4; ++g) {
            const int jg = g * NU + (uvalid ? jl : 0);
#pragma unroll
            for (int c = 0; c < 4; ++c) {
                s16x8 h8, l8;
#pragma unroll
                for (int e = 0; e < 8; ++e) {
                    const int k = c * 32 + (lane >> 4) * 8 + e;
                    float x = 0.f;
                    if (uvalid) {
                        if (k < NU)        x = rk[k * NJ + jg];
                        else if (k < 116)  x = k_lstm[(k - NU) * NJ + jg];
                        else if (k == 116) x = b_lstm[jg];
                    }
                    const unsigned short hb = f2bf(x);
                    h8[e] = (short)hb;
                    l8[e] = (short)f2bf(x - bf2f(hb));
                }
                bhi[g][c] = h8; blo[g][c] = l8;
            }
        }
    }
    __syncthreads();   // a_lds zeroing complete

    // p(t=0) into buf 0; bias slot k=116 into both buffers
    if (tid < 256) {
        const int pb = tid >> 4, pf = tid & 15;
        const float pv = p_in[(size_t)(b0 + pb) * (NS * NF) + pf];
        const int k = 100 + pf;
        a_lds[0][k >> 5][(((k >> 3) & 3) << 4) + pb][k & 7] = f2bf(pv);
    }
    if (tid < NBB) {
        a_lds[0][3][32 + tid][4] = 0x3F80;
        a_lds[1][3][32 + tid][4] = 0x3F80;
    }
    float cst[4] = {0.f, 0.f, 0.f, 0.f};
    __syncthreads();

#pragma unroll 1
    for (int t = 0; t < NS; ++t) {
        const int cur = t & 1, nxt = cur ^ 1;
        if (wid == 7) {
            // prefetch+write p(t+1) into the next buffer
            if (t + 1 < NS) {
#pragma unroll
                for (int r = 0; r < 4; ++r) {
                    const int idx = (tid - 448) + 64 * r;
                    const int pb = idx >> 4, pf = idx & 15;
                    const float pv =
                        p_in[(size_t)(b0 + pb) * (NS * NF) + (t + 1) * NF + pf];
                    const int k = 100 + pf;
                    a_lds[nxt][k >> 5][(((k >> 3) & 3) << 4) + pb][k & 7] = f2bf(pv);
                }
            }
        } else {
            s16x8 ah[4];
#pragma unroll
            for (int c = 0; c < 4; ++c) ah[c] = ((const s16x8*)a_lds[cur][c])[lane];
            f32x4v acc[4];
#pragma unroll
            for (int g = 0; g < 4; ++g) {
                f32x4v z = {0.f, 0.f, 0.f, 0.f};
#pragma unroll
                for (int c = 0; c < 4; ++c) {
                    z = __builtin_amdgcn_mfma_f32_16x16x32_bf16(ah[c], bhi[g][c], z, 0, 0, 0);
                    z = __builtin_amdgcn_mfma_f32_16x16x32_bf16(ah[c], blo[g][c], z, 0, 0, 0);
                }
                acc[g] = z;
            }
            // in-register gates: lane owns unit jl, batches 4*(lane>>4)+q
            const int c_  = jl >> 5;
            const int lsb = ((jl >> 3) & 3) << 4;
            const int e_  = jl & 7;
#pragma unroll
            for (int q = 0; q < 4; ++q) {
                const float zi = acc[0][q], zf = acc[1][q];
                const float zg = acc[2][q], zo = acc[3][q];
                const float ig  = 1.f / (1.f + __expf(-zi));
                const float fg_ = 1.f / (1.f + __expf(-zf));
                const float og  = 1.f / (1.f + __expf(-zo));
                cst[q] = fg_ * cst[q] + ig * leaky(zg);
                const float h = og * leaky(cst[q]);
                if (uvalid) {
                    const int bb = ((lane >> 4) << 2) + q;
                    a_lds[nxt][c_][lsb + bb][e_] = f2bf(h);
                    if (t == NS - 1) h_f32[bb][jl] = h;
                }
            }
        }
        __syncthreads();
    }

    // dense head: d = tanh(h @ w1 + b1), 1024 outputs / 512 threads
#pragma unroll
    for (int r = 0; r < 2; ++r) {
        const int o = tid + 512 * r;
        const int hb = o >> 6, m = o & 63;
        float a = b1[m];
#pragma unroll 4
        for (int u = 0; u < NU; ++u) a += h_f32[hb][u] * w1[u * 64 + m];
        d_lds[o] = tanhf(a);
    }
    __syncthreads();

    // logits + softmax (3 classes)
    if (tid < NBB) {
        float l0 = b2[0], l1 = b2[1], l2 = b2[2];
        for (int m = 0; m < 64; ++m) {
            const float d = d_lds[tid * 64 + m];
            l0 += d * w2[m * 3 + 0];
            l1 += d * w2[m * 3 + 1];
            l2 += d * w2[m * 3 + 2];
        }
        const float mx = fmaxf(l0, fmaxf(l1, l2));
        const float e0 = __expf(l0 - mx), e1 = __expf(l1 - mx), e2 = __expf(l2 - mx);
        const float inv = 1.f / (e0 + e1 + e2);
        out[(b0 + tid) * 3 + 0] = e0 * inv;
        out[(b0 + tid) * 3 + 1] = e1 * inv;
        out[(b0 + tid) * 3 + 2] = e2 * inv;
    }
}

extern "C" void kernel_launch(void* const* d_in, const int* in_sizes, int n_in,
                              void* d_out, int out_size, void* d_ws, size_t ws_size,
                              hipStream_t stream) {
    const int*   tokens = (const int*)  d_in[0];
    const float* emb    = (const float*)d_in[1];
    const float* conv_w = (const float*)d_in[2];
    const float* conv_b = (const float*)d_in[3];
    const float* k_lstm = (const float*)d_in[4];
    const float* rk     = (const float*)d_in[5];
    const float* b_lstm = (const float*)d_in[6];
    const float* w1     = (const float*)d_in[7];
    const float* b1     = (const float*)d_in[8];
    const float* w2     = (const float*)d_in[9];
    const float* b2     = (const float*)d_in[10];
    float* out = (float*)d_out;

    // ws layout (bytes): p[1024][25][16] f32 : [0, 1638400)
    //                    emb_h (half2)       : [1638400, 4687400) -> align 4687408
    //                    convw_h (half2)     : [4687408, 4721264)
    char* ws = (char*)d_ws;
    float*        p_ws    = (float*)ws;
    unsigned int* emb_h   = (unsigned int*)(ws + 1638400);
    unsigned int* convw_h = (unsigned int*)(ws + 4687408);

    prep_kernel<<<1024, 256, 0, stream>>>(emb, conv_w, emb_h, convw_h);
    conv_embed_kernel<<<B_, 256, 0, stream>>>(tokens, emb_h, convw_h, conv_b, p_ws);
    lstm_mfma_kernel<<<B_ / NBB, 512, 0, stream>>>(p_ws, k_lstm, rk, b_lstm,
                                                   w1, b1, w2, b2, out);
}